// Round 19
// baseline (5580.973 us; speedup 1.0000x reference)
//
#include <hip/hip_runtime.h>
#include <math.h>

#define NWG 256
#define TPB 512
#define BSLOT 32   // uints per 128B barrier slot

static constexpr int H    = 2048;
static constexpr int H3   = 6144;
static constexpr int TDIM = 1024;
static constexpr int TSEQ = 512;
static constexpr int NL   = 50000;
static constexpr int ML   = 50;
static constexpr int DK   = 4096;

typedef unsigned int v4u __attribute__((ext_vector_type(4)));

// workspace layout (bytes, 16B aligned)
static constexpr size_t OFF_EMB  = 0;
static constexpr size_t OFF_GI   = OFF_EMB + (size_t)TSEQ * TDIM * 4;   // 2 MB
static constexpr size_t OFF_BAR  = OFF_GI + (size_t)2 * TSEQ * H3 * 4;  // +25.2 MB
static constexpr size_t OFF_HBF  = OFF_BAR + (size_t)64 * BSLOT * 4;    // 8 KB barrier block
static constexpr size_t OFF_HBB  = OFF_HBF + (size_t)2 * H * 4;
static constexpr size_t OFF_HF   = OFF_HBB + (size_t)2 * H * 4;
static constexpr size_t OFF_HB   = OFF_HF + (size_t)H * 4;
static constexpr size_t OFF_SENT = OFF_HB + (size_t)H * 4;
static constexpr size_t OFF_HD   = OFF_SENT + (size_t)H * 4;
static constexpr size_t OFF_WBV  = OFF_HD + (size_t)H * 4;
static constexpr size_t OFF_WBI  = OFF_WBV + (size_t)NWG * 4;
static constexpr size_t OFF_ONE  = OFF_WBI + (size_t)NWG * 4;
static constexpr size_t OFF_WL16 = ((OFF_ONE + 64) + 255) & ~(size_t)255;
static constexpr size_t WS_NEED  = OFF_WL16;                             // ~27.5 MB
static constexpr size_t WS_BIG   = OFF_WL16 + (size_t)NL * H * 2;        // +204.8 MB

// ---------- device-coherent (sc0 sc1) ops: mutable cross-WG data only ----------
__device__ __forceinline__ float4 cld4(const float4* p) {
  float4 v;
  asm volatile("global_load_dwordx4 %0, %1, off sc0 sc1\n\ts_waitcnt vmcnt(0)"
               : "=v"(v) : "v"(p) : "memory");
  return v;
}
__device__ __forceinline__ float cld1(const float* p) {
  float v;
  asm volatile("global_load_dword %0, %1, off sc0 sc1\n\ts_waitcnt vmcnt(0)"
               : "=v"(v) : "v"(p) : "memory");
  return v;
}
__device__ __forceinline__ int cldi(const int* p) {
  int v;
  asm volatile("global_load_dword %0, %1, off sc0 sc1\n\ts_waitcnt vmcnt(0)"
               : "=v"(v) : "v"(p) : "memory");
  return v;
}
__device__ __forceinline__ void cst1(float* p, float v) {
  asm volatile("global_store_dword %0, %1, off sc0 sc1" :: "v"(p), "v"(v) : "memory");
}
__device__ __forceinline__ void csti(int* p, int v) {
  asm volatile("global_store_dword %0, %1, off sc0 sc1" :: "v"(p), "v"(v) : "memory");
}

__device__ __forceinline__ float dp4(float4 a, float4 b, float s) {
  s = fmaf(a.x, b.x, s);
  s = fmaf(a.y, b.y, s);
  s = fmaf(a.z, b.z, s);
  s = fmaf(a.w, b.w, s);
  return s;
}
__device__ __forceinline__ float wred(float s) {
  #pragma unroll
  for (int m = 32; m > 0; m >>= 1) s += __shfl_xor(s, m, 64);
  return s;
}
__device__ __forceinline__ float u2lo(unsigned u) { return __uint_as_float(u << 16); }
__device__ __forceinline__ float u2hi(unsigned u) { return __uint_as_float(u & 0xffff0000u); }

// ---- named-register weight tiers ----
#define DECL8(p)  float4 p##0, p##1, p##2, p##3, p##4, p##5, p##6, p##7
#define LOAD8(p, base) do { const float4* _r = (base); \
  p##0 = _r[lane];       p##1 = _r[lane + 64];  p##2 = _r[lane + 128]; \
  p##3 = _r[lane + 192]; p##4 = _r[lane + 256]; p##5 = _r[lane + 320]; \
  p##6 = _r[lane + 384]; p##7 = _r[lane + 448]; } while (0)
#define SC4(v) do { (v).x *= one; (v).y *= one; (v).z *= one; (v).w *= one; } while (0)
#define SCALE8(p) do { SC4(p##0); SC4(p##1); SC4(p##2); SC4(p##3); \
                       SC4(p##4); SC4(p##5); SC4(p##6); SC4(p##7); } while (0)
// encoder step: acc a0r,a0z,a0n (regs) a1r,a1z (LDS) a1n (stream, L2-cached)
#define STEPK(k) { float4 hv = h4[lane + (k << 6)]; \
  a0r = dp4(wA##k, hv, a0r); \
  a0z = dp4(wB##k, hv, a0z); \
  a0n = dp4(wC##k, hv, a0n); \
  a1r = dp4(lwW[((k) << 6) + lane], hv, a1r); \
  a1z = dp4(lwW[(((k) + 8) << 6) + lane], hv, a1z); \
  a1n = dp4(rN1[lane + ((k) << 6)], hv, a1n); }
// decoder phase-A steps (k 0..7 and 8..15), per-accumulator k-ascending order
#define DSTEPA(k) { float4 cv = c4[lane + ((k) << 6)]; \
  s0 = dp4(wRa##k, cv, s0); \
  s1 = dp4(wZa##k, cv, s1); \
  s2 = dp4(lwW[512 + ((k) << 6) + lane], cv, s2); }
#define DSTEPB(j) { float4 cv = c4[lane + (((j) + 8) << 6)]; \
  s0 = dp4(wRb##j, cv, s0); \
  s1 = dp4(lwW[((j) << 6) + lane], cv, s1); \
  s2 = dp4(rN2[lane + ((j) << 6)], cv, s2); }

// MONOTONE FENCE-FREE barrier: RELAXED agent atomics only, counters never
// reset, waiters poll top >= phase*nGrp. No release/acquire -> no per-step
// L2 writeback/invalidate. Mutable data moves via sc0sc1.
__device__ __forceinline__ void hbar(unsigned* bar, int gslot, int tslot,
                                     unsigned phase, unsigned grpSize, unsigned nGrp) {
  __syncthreads();
  if (threadIdx.x == 0) {
    unsigned a = __hip_atomic_fetch_add(bar + (size_t)gslot * BSLOT, 1u,
                                        __ATOMIC_RELAXED, __HIP_MEMORY_SCOPE_AGENT);
    if (a == phase * grpSize - 1u)
      __hip_atomic_fetch_add(bar + (size_t)tslot * BSLOT, 1u,
                             __ATOMIC_RELAXED, __HIP_MEMORY_SCOPE_AGENT);
    unsigned c;
    do {
      __builtin_amdgcn_s_sleep(1);
      c = __hip_atomic_load(bar + (size_t)tslot * BSLOT,
                            __ATOMIC_RELAXED, __HIP_MEMORY_SCOPE_AGENT);
    } while (c < phase * nGrp);
    asm volatile("" ::: "memory");
  }
  __syncthreads();
}

__global__ __launch_bounds__(256) void k_gather(const int* __restrict__ x,
                                                const float* __restrict__ E,
                                                float* __restrict__ emb,
                                                unsigned* __restrict__ bar,
                                                float* __restrict__ onep) {
  if (blockIdx.x == 0) {
    for (int i = threadIdx.x; i < 64 * BSLOT; i += 256) bar[i] = 0u;
    if (threadIdx.x == 0) *onep = 1.0f;   // opaque runtime 1.0
  }
  int t = blockIdx.x;
  const float4* src = (const float4*)(E + (size_t)x[t] * TDIM);
  float4* dst = (float4*)(emb + (size_t)t * TDIM);
  dst[threadIdx.x] = src[threadIdx.x];
}

// one-time W_last fp32 -> bf16 (RTNE), row-major
__global__ __launch_bounds__(256) void k_cast(const float* __restrict__ W,
                                              unsigned short* __restrict__ O) {
  size_t i = (size_t)blockIdx.x * 2048 + (size_t)threadIdx.x * 8;
  float4 a = ((const float4*)(W + i))[0];
  float4 b = ((const float4*)(W + i))[1];
  #define CVT(f) ((( __float_as_uint(f) + 0x7FFFu + ((__float_as_uint(f) >> 16) & 1u)) >> 16) & 0xFFFFu)
  uint4 o;
  o.x = CVT(a.x) | (CVT(a.y) << 16);
  o.y = CVT(a.z) | (CVT(a.w) << 16);
  o.z = CVT(b.x) | (CVT(b.y) << 16);
  o.w = CVT(b.z) | (CVT(b.w) << 16);
  #undef CVT
  ((uint4*)(O + i))[0] = o;
}

// GI[dir][t][j] = emb[(dir? 511-t : t)] . Wih_dir[j] + bih_dir[j]
__global__ __launch_bounds__(256) void k_gi(const float* __restrict__ emb,
                                            const float* __restrict__ Wf,
                                            const float* __restrict__ bf_,
                                            const float* __restrict__ Wb,
                                            const float* __restrict__ bb_,
                                            float* __restrict__ GI) {
  __shared__ float As[64][33];
  __shared__ float Bs[64][33];
  const int dir = blockIdx.z;
  const float* W  = dir ? Wb  : Wf;
  const float* bi = dir ? bb_ : bf_;
  const int t0 = blockIdx.x * 64, j0 = blockIdx.y * 64;
  const int tid = threadIdx.x;
  const int tx = tid & 15, ty = tid >> 4;
  float acc[4][4] = {};
  for (int k0 = 0; k0 < TDIM; k0 += 32) {
    #pragma unroll
    for (int i = 0; i < 8; ++i) {
      int idx = tid + (i << 8);
      int r = idx >> 5, kk = idx & 31;
      int tg = t0 + r;
      int arow = dir ? (TSEQ - 1 - tg) : tg;
      As[r][kk] = emb[(size_t)arow * TDIM + k0 + kk];
      Bs[r][kk] = W[(size_t)(j0 + r) * TDIM + k0 + kk];
    }
    __syncthreads();
    #pragma unroll
    for (int kk = 0; kk < 32; ++kk) {
      float a[4], b[4];
      #pragma unroll
      for (int i = 0; i < 4; ++i) a[i] = As[ty * 4 + i][kk];
      #pragma unroll
      for (int jj = 0; jj < 4; ++jj) b[jj] = Bs[tx * 4 + jj][kk];
      #pragma unroll
      for (int i = 0; i < 4; ++i)
        #pragma unroll
        for (int jj = 0; jj < 4; ++jj) acc[i][jj] = fmaf(a[i], b[jj], acc[i][jj]);
    }
    __syncthreads();
  }
  float* C = GI + (size_t)dir * TSEQ * H3;
  #pragma unroll
  for (int i = 0; i < 4; ++i)
    #pragma unroll
    for (int jj = 0; jj < 4; ++jj) {
      int t = t0 + ty * 4 + i, col = j0 + tx * 4 + jj;
      C[(size_t)t * H3 + col] = acc[i][jj] + bi[col];
    }
}

// ===================== ENCODER-ONLY persistent kernel (round-14, unchanged) ====
__global__ __launch_bounds__(TPB, 2) void k_enc(
    const float* __restrict__ Whh_f, const float* __restrict__ bhh_f,
    const float* __restrict__ Whh_b, const float* __restrict__ bhh_b,
    const float* __restrict__ GI,
    float* __restrict__ hbF, float* __restrict__ hbB,
    float* __restrict__ hF, float* __restrict__ hB,
    unsigned* __restrict__ bar, const float* __restrict__ onep) {
  __shared__ float  ldsH[H];                // 8 KB (h broadcast)
  __shared__ float4 ldsW[8 * 16 * 64];      // 128 KB (weight tier 2)
  const int tid  = threadIdx.x;
  const int wg   = blockIdx.x;
  const int lane = tid & 63;
  const int w    = tid >> 6;
  const float4* h4 = (const float4*)ldsH;
  const float one = *onep;    // opaque 1.0f (SGPR)

  const int d   = wg >> 7;          // 0=fwd, 1=bwd
  const int wid = wg & 127;
  const int j0  = (((wid << 3) | w) << 1);   // this wave's 2 h-indices
  const float* Whh = d ? Whh_b : Whh_f;
  const float* bhh = d ? bhh_b : bhh_f;
  const float* GId = GI + (size_t)d * TSEQ * H3;
  float* hbufD = d ? hbB : hbF;
  float* hT    = d ? hB  : hF;
  const int gslot = d * 16 + (wid & 7), tslot = d * 16 + 8;
  unsigned ep = 0;

  // tier 1: rows r0,z0,n0 -> 24 NAMED float4 (96 VGPRs)
  DECL8(wA); DECL8(wB); DECL8(wC);
  LOAD8(wA, (const float4*)(Whh + (size_t)(0 * H + j0 + 0) * H));
  LOAD8(wB, (const float4*)(Whh + (size_t)(1 * H + j0 + 0) * H));
  LOAD8(wC, (const float4*)(Whh + (size_t)(2 * H + j0 + 0) * H));

  // tier 2: rows r1,z1 -> LDS (per-wave 16 KB block, lane-major, conflict-free)
  float4* lwW = &ldsW[(size_t)w << 10];    // w * 1024 float4
  {
    const float4* rR1 = (const float4*)(Whh + (size_t)(0 * H + j0 + 1) * H);
    const float4* rZ1 = (const float4*)(Whh + (size_t)(1 * H + j0 + 1) * H);
    #pragma unroll
    for (int k = 0; k < 8; ++k) lwW[(k << 6) + lane]       = rR1[lane + (k << 6)];
    #pragma unroll
    for (int k = 0; k < 8; ++k) lwW[((k + 8) << 6) + lane] = rZ1[lane + (k << 6)];
  }

  // tier 3: row n1 -> streamed each step (plain loads; 2.1 MB/XCD -> L2-hit)
  const float4* rN1 = (const float4*)(Whh + (size_t)(2 * H + j0 + 1) * H);

  float b_r = 0.f, b_z = 0.f, b_n = 0.f, g_r = 0.f, g_z = 0.f, g_n = 0.f;
  if (lane < 2) {
    b_r = bhh[j0 + lane]; b_z = bhh[H + j0 + lane]; b_n = bhh[2 * H + j0 + lane];
    g_r = GId[j0 + lane]; g_z = GId[H + j0 + lane]; g_n = GId[2 * H + j0 + lane];
  }
  // t = 0: h(0)=0 -> h(1) directly, no matvec, no prior barrier
  if (lane < 2) {
    float r = 1.f / (1.f + expf(-(g_r + b_r)));
    float z = 1.f / (1.f + expf(-(g_z + b_z)));
    float n = tanhf(g_n + r * b_n);
    cst1(&hbufD[H + j0 + lane], (1.f - z) * n);
    const float* gp = GId + (size_t)1 * H3 + j0 + lane;
    g_r = gp[0]; g_z = gp[H]; g_n = gp[2 * H];
  }
  hbar(bar, gslot, tslot, ++ep, 16u, 8u);   // also covers the LDS weight fill

  for (int t = 1; t < TSEQ; ++t) {
    // loop-carried x1.0 on the register tier: loads cannot be re-sunk
    SCALE8(wA); SCALE8(wB); SCALE8(wC);

    ((float4*)ldsH)[tid] = cld4((const float4*)hbufD + ((t & 1) << 9) + tid);
    __syncthreads();
    float a0r = 0.f, a0z = 0.f, a0n = 0.f, a1r = 0.f, a1z = 0.f, a1n = 0.f;
    STEPK(0) STEPK(1) STEPK(2) STEPK(3) STEPK(4) STEPK(5) STEPK(6) STEPK(7)
    a0r = wred(a0r); a0z = wred(a0z); a0n = wred(a0n);
    a1r = wred(a1r); a1z = wred(a1z); a1n = wred(a1n);
    if (lane < 2) {
      float aR = lane ? a1r : a0r;
      float aZ = lane ? a1z : a0z;
      float aN = lane ? a1n : a0n;
      float hold = ldsH[j0 + lane];
      float r = 1.f / (1.f + expf(-(g_r + b_r + aR)));
      float z = 1.f / (1.f + expf(-(g_z + b_z + aZ)));
      float n = tanhf(g_n + r * (aN + b_n));
      cst1(&hbufD[(size_t)((t + 1) & 1) * H + j0 + lane], (1.f - z) * n + z * hold);
      if (t < TSEQ - 1) {
        const float* gp = GId + (size_t)(t + 1) * H3 + j0 + lane;
        g_r = gp[0]; g_z = gp[H]; g_n = gp[2 * H];
      }
    }
    hbar(bar, gslot, tslot, ++ep, 16u, 8u);
  }
  if (wid == 0) {   // final h = buf0 (coherent read; plain store, kernel-end flush)
    float4 hv = cld4((const float4*)hbufD + tid);
    ((float4*)hT)[tid] = hv;
  }
}

// ===================== mid/len + decoder kernel ==============================
// Phase A: Wih_d pinned on-chip (tier1 96 VGPRs + tier2 16 KB/wave LDS +
// tier3 8 KB/wave L2-resident stream) -> no HBM traffic. Phase B: register-
// staged hvb (conflict-free) + cached Wl16 stream + nt score stores.
template <int BF16>
__global__ __launch_bounds__(TPB, 2) void k_dec(
    const float* __restrict__ W_mid, const float* __restrict__ b_mid,
    const float* __restrict__ W_len, const float* __restrict__ b_len,
    const float* __restrict__ Wih_d, const float* __restrict__ bih_d,
    const float* __restrict__ bhh_d,
    const float* __restrict__ W_last, const unsigned short* __restrict__ Wl16,
    const float* __restrict__ L,
    float* __restrict__ out,
    const float* __restrict__ hF, const float* __restrict__ hB,
    float* __restrict__ sent, float* __restrict__ hD,
    float* __restrict__ wbV, int* __restrict__ wbI,
    unsigned* __restrict__ bar, const float* __restrict__ onep) {
  __shared__ float  ldsH[H];            // 8 KB
  __shared__ float  ldsC[2 * H];        // 16 KB (carry)
  __shared__ float4 ldsW[8 * 1024];     // 128 KB (Wih_d tier 2)
  __shared__ float rv[NWG];
  __shared__ int   ri[NWG];
  __shared__ float tv1[8], tv2[8];
  __shared__ int   ti1[8], ti2[8];
  __shared__ float scV[2];
  __shared__ int   scI[2];

  const int tid  = threadIdx.x;
  const int wg   = blockIdx.x;
  const int lane = tid & 63;
  const int w    = tid >> 6;
  const float4* h4 = (const float4*)ldsH;
  const int jd = (wg << 3) | w;   // decoder/mid h-index, 1 per wave
  const float one = *onep;        // opaque 1.0f
  unsigned fp = 0;

  // ---- Wih_d row triple for jd: tier1 regs / tier2 LDS / tier3 stream ----
  const float4* rowR = (const float4*)Wih_d + (size_t)jd * (DK / 4);
  const float4* rowZ = rowR + (size_t)H * (DK / 4);
  const float4* rowN = rowZ + (size_t)H * (DK / 4);
  DECL8(wRa); DECL8(wRb); DECL8(wZa);
  LOAD8(wRa, rowR);        // r-gate, k 0..7
  LOAD8(wRb, rowR + 512);  // r-gate, k 8..15
  LOAD8(wZa, rowZ);        // z-gate, k 0..7
  float4* lwW = &ldsW[(size_t)w << 10];   // per-wave 1024 float4
  {
    #pragma unroll
    for (int k = 0; k < 8; ++k) lwW[(k << 6) + lane]       = rowZ[512 + (k << 6) + lane]; // z k8..15
    #pragma unroll
    for (int k = 0; k < 8; ++k) lwW[512 + (k << 6) + lane] = rowN[(k << 6) + lane];       // n k0..7
  }
  const float4* rN2 = rowN + 512;   // n-gate k 8..15, streamed (L2-resident)

  // ---------------- sent = [hF,hB] @ W_mid.T + b_mid ----------------
  ((float4*)ldsC)[tid]       = ((const float4*)hF)[tid];   // kernel-boundary coherent
  ((float4*)ldsC)[TPB + tid] = ((const float4*)hB)[tid];
  __syncthreads();
  {
    const float4* wm = (const float4*)W_mid + (size_t)jd * (DK / 4);
    const float4* c4 = (const float4*)ldsC;
    float s = 0.f;
    #pragma unroll
    for (int k = 0; k < 16; ++k) {
      int c = lane + (k << 6);
      s = dp4(wm[c], c4[c], s);
    }
    s = wred(s);
    if (lane == 0) cst1(&sent[jd], s + b_mid[jd]);
  }
  hbar(bar, 32 + (wg & 7), 40, ++fp, 32u, 8u);

  // stage sent -> ldsH (lscores + A(0) carry tail)
  ((float4*)ldsH)[tid] = cld4((const float4*)sent + tid);
  __syncthreads();

  // ---------------- lscores ----------------
  if (jd < ML) {
    const float4* wl = (const float4*)W_len + (size_t)jd * (H / 4);
    float s = 0.f;
    #pragma unroll
    for (int k = 0; k < 8; ++k) {
      int c = lane + (k << 6);
      s = dp4(wl[c], h4[c], s);
    }
    s = wred(s);
    if (lane == 0) out[jd] = s + b_len[jd];
  }

  // decoder per-wave gate constants (decoder h0 = 0 -> gh == bhh_d)
  float cr = 0.f, cz = 0.f, cni = 0.f, cnh = 0.f;
  if (lane == 0) {
    cr  = bih_d[jd] + bhh_d[jd];
    cz  = bih_d[H + jd] + bhh_d[H + jd];
    cni = bih_d[2 * H + jd];
    cnh = bhh_d[2 * H + jd];
  }

  // A(0) carry: head = 0, tail = sent
  ((float4*)ldsC)[tid]       = make_float4(0.f, 0.f, 0.f, 0.f);
  ((float4*)ldsC)[TPB + tid] = ((const float4*)ldsH)[tid];
  __syncthreads();

  // ---------------- decoder: 50 steps, 2 barriers each ----------------
  for (int st = 0; st < ML; ++st) {
    if (st > 0) {
      // local finalize of previous step's argmax in every WG
      if (tid < NWG) { rv[tid] = cld1(wbV + tid); ri[tid] = cldi(wbI + tid); }
      __syncthreads();
      for (int off = NWG / 2; off > 0; off >>= 1) {
        if (tid < off) {
          float v2 = rv[tid + off]; int i2 = ri[tid + off];
          if (v2 > rv[tid] || (v2 == rv[tid] && i2 < ri[tid])) { rv[tid] = v2; ri[tid] = i2; }
        }
        __syncthreads();
      }
      int pred = ri[0];
      if (wg == 0 && tid == 0) out[ML + (size_t)ML * NL + (st - 1)] = (float)pred;
      // carry: head = hD(st-1) (still in ldsH), tail = L[pred] (read-only input)
      ((float4*)ldsC)[tid]       = ((const float4*)ldsH)[tid];
      ((float4*)ldsC)[TPB + tid] = ((const float4*)(L + (size_t)pred * H))[tid];
      __syncthreads();
    }
    // phase A: gi = Wih_d @ carry from on-chip tiers; gates; publish hD.
    // Per-accumulator addition order is k-ascending (identical to streaming).
    {
      SCALE8(wRa); SCALE8(wRb); SCALE8(wZa);   // loop-carried: no re-sink
      const float4* c4 = (const float4*)ldsC;
      float s0 = 0.f, s1 = 0.f, s2 = 0.f;
      DSTEPA(0) DSTEPA(1) DSTEPA(2) DSTEPA(3)
      DSTEPA(4) DSTEPA(5) DSTEPA(6) DSTEPA(7)
      DSTEPB(0) DSTEPB(1) DSTEPB(2) DSTEPB(3)
      DSTEPB(4) DSTEPB(5) DSTEPB(6) DSTEPB(7)
      s0 = wred(s0); s1 = wred(s1); s2 = wred(s2);
      if (lane == 0) {
        float r = 1.f / (1.f + expf(-(s0 + cr)));
        float z = 1.f / (1.f + expf(-(s1 + cz)));
        float n = tanhf(s2 + cni + r * cnh);
        cst1(&hD[jd], (1.f - z) * n);
      }
    }
    hbar(bar, 32 + (wg & 7), 40, ++fp, 32u, 8u);   // hD visible

    // phase B: scores = hD @ W_last.T ; argmax candidates
    ((float4*)ldsH)[tid] = cld4((const float4*)hD + tid);
    __syncthreads();
    float* outs = out + ML + (size_t)st * NL;
    if (BF16) {
      // register-staged h (conflict-free) + cached Wl16 + nt score stores
      float4 hvb[8];
      #pragma unroll
      for (int k = 0; k < 4; ++k) {
        int i = (lane + (k << 6)) << 1;
        hvb[2 * k]     = h4[i];
        hvb[2 * k + 1] = h4[i + 1];
      }
      float v1 = -3.4e38f, v2 = -3.4e38f;
      int   i1 = 0x7FFFFFFF, i2 = 0x7FFFFFFF;
      for (int chunk = 0; chunk < 25; ++chunk) {
        int r = (chunk << 11) + jd;
        if (r < NL) {
          const uint4* row = (const uint4*)(Wl16 + (size_t)r * H);
          float sc = 0.f;
          #pragma unroll
          for (int k = 0; k < 4; ++k) {
            uint4 u = row[lane + (k << 6)];
            float4 ha = hvb[2 * k], hb = hvb[2 * k + 1];
            sc = fmaf(u2lo(u.x), ha.x, sc); sc = fmaf(u2hi(u.x), ha.y, sc);
            sc = fmaf(u2lo(u.y), ha.z, sc); sc = fmaf(u2hi(u.y), ha.w, sc);
            sc = fmaf(u2lo(u.z), hb.x, sc); sc = fmaf(u2hi(u.z), hb.y, sc);
            sc = fmaf(u2lo(u.w), hb.z, sc); sc = fmaf(u2hi(u.w), hb.w, sc);
          }
          sc = wred(sc);
          if (lane == 0) __builtin_nontemporal_store(sc, &outs[r]);
          if (sc > v1 || (sc == v1 && r < i1)) { v2 = v1; i2 = i1; v1 = sc; i1 = r; }
          else if (sc > v2 || (sc == v2 && r < i2)) { v2 = sc; i2 = r; }
        }
      }
      if (lane == 0) { tv1[w] = v1; ti1[w] = i1; tv2[w] = v2; ti2[w] = i2; }
      __syncthreads();
      if (tid == 0) {   // WG top-2 by approx score
        float b1 = -3.4e38f, b2 = -3.4e38f;
        int   x1 = 0x7FFFFFFF, x2 = 0x7FFFFFFF;
        #pragma unroll
        for (int q = 0; q < 8; ++q) {
          float a1 = tv1[q]; int y1 = ti1[q];
          float a2 = tv2[q]; int y2 = ti2[q];
          if (a1 > b1 || (a1 == b1 && y1 < x1)) { b2 = b1; x2 = x1; b1 = a1; x1 = y1; }
          else if (a1 > b2 || (a1 == b2 && y1 < x2)) { b2 = a1; x2 = y1; }
          if (a2 > b1 || (a2 == b1 && y2 < x1)) { b2 = b1; x2 = x1; b1 = a2; x1 = y2; }
          else if (a2 > b2 || (a2 == b2 && y2 < x2)) { b2 = a2; x2 = y2; }
        }
        scI[0] = x1; scI[1] = x2;
      }
      __syncthreads();
      if (w < 2) {   // exact fp32 rescore (identical sum order everywhere)
        int c = scI[w];
        const float4* wl = (const float4*)W_last + (size_t)c * (H / 4);
        float s = 0.f;
        #pragma unroll
        for (int k = 0; k < 8; ++k) {
          int cc = lane + (k << 6);
          s = dp4(wl[cc], h4[cc], s);
        }
        s = wred(s);
        if (lane == 0) scV[w] = s;
      }
      __syncthreads();
      if (tid == 0) {
        float v = scV[0]; int i0 = scI[0];
        if (scV[1] > v || (scV[1] == v && scI[1] < i0)) { v = scV[1]; i0 = scI[1]; }
        cst1(&wbV[wg], v); csti(&wbI[wg], i0);
      }
    } else {
      // fp32 fallback (ws too small for bf16 copy)
      float bv = -3.4e38f; int bix = 0x7FFFFFFF;
      for (int chunk = 0; chunk < 25; ++chunk) {
        int r = (chunk << 11) + jd;
        if (r < NL) {
          const float4* wl = (const float4*)W_last + (size_t)r * (H / 4);
          float sc = 0.f;
          #pragma unroll
          for (int k = 0; k < 8; ++k) {
            int c = lane + (k << 6);
            sc = dp4(wl[c], h4[c], sc);
          }
          sc = wred(sc);
          if (lane == 0) {
            outs[r] = sc;
            if (sc > bv) { bv = sc; bix = r; }
          }
        }
      }
      if (lane == 0) { tv1[w] = bv; ti1[w] = bix; }
      __syncthreads();
      if (tid == 0) {
        float v = tv1[0]; int i0 = ti1[0];
        #pragma unroll
        for (int q = 1; q < 8; ++q)
          if (tv1[q] > v || (tv1[q] == v && ti1[q] < i0)) { v = tv1[q]; i0 = ti1[q]; }
        cst1(&wbV[wg], v); csti(&wbI[wg], i0);
      }
    }
    hbar(bar, 32 + (wg & 7), 40, ++fp, 32u, 8u);   // wb visible
  }

  // final pred (st = 49)
  if (wg == 0) {
    if (tid < NWG) { rv[tid] = cld1(wbV + tid); ri[tid] = cldi(wbI + tid); }
    __syncthreads();
    for (int off = NWG / 2; off > 0; off >>= 1) {
      if (tid < off) {
        float v2 = rv[tid + off]; int i2 = ri[tid + off];
        if (v2 > rv[tid] || (v2 == rv[tid] && i2 < ri[tid])) { rv[tid] = v2; ri[tid] = i2; }
      }
      __syncthreads();
    }
    if (tid == 0) out[ML + (size_t)ML * NL + (ML - 1)] = (float)ri[0];
  }
}

extern "C" void kernel_launch(void* const* d_in, const int* in_sizes, int n_in,
                              void* d_out, int out_size, void* d_ws, size_t ws_size,
                              hipStream_t stream) {
  (void)in_sizes; (void)n_in; (void)out_size;
  if (ws_size < WS_NEED) return;
  const bool big = (ws_size >= WS_BIG);

  const int*   x     = (const int*)  d_in[0];
  const float* E     = (const float*)d_in[1];
  const float* L     = (const float*)d_in[2];
  const float* Wih_f = (const float*)d_in[3];
  const float* Whh_f = (const float*)d_in[4];
  const float* bih_f = (const float*)d_in[5];
  const float* bhh_f = (const float*)d_in[6];
  const float* Wih_b = (const float*)d_in[7];
  const float* Whh_b = (const float*)d_in[8];
  const float* bih_b = (const float*)d_in[9];
  const float* bhh_b = (const float*)d_in[10];
  const float* W_mid = (const float*)d_in[11];
  const float* b_mid = (const float*)d_in[12];
  const float* W_len = (const float*)d_in[13];
  const float* b_len = (const float*)d_in[14];
  const float* Wih_d = (const float*)d_in[15];
  // d_in[16] = Whh_d: unused (decoder hidden is 0 -> gh == bhh_d)
  const float* bih_d = (const float*)d_in[17];
  const float* bhh_d = (const float*)d_in[18];
  const float* W_last= (const float*)d_in[19];
  float* out = (float*)d_out;
  char* ws = (char*)d_ws;

  float*    emb  = (float*)(ws + OFF_EMB);
  float*    GIp  = (float*)(ws + OFF_GI);
  unsigned* bar  = (unsigned*)(ws + OFF_BAR);
  float*    hbF  = (float*)(ws + OFF_HBF);
  float*    hbB  = (float*)(ws + OFF_HBB);
  float*    hF   = (float*)(ws + OFF_HF);
  float*    hB   = (float*)(ws + OFF_HB);
  float*    sent = (float*)(ws + OFF_SENT);
  float*    hD   = (float*)(ws + OFF_HD);
  float*    wbV  = (float*)(ws + OFF_WBV);
  int*      wbI  = (int*)  (ws + OFF_WBI);
  float*    onep = (float*)(ws + OFF_ONE);
  unsigned short* wl16 = (unsigned short*)(ws + OFF_WL16);

  hipLaunchKernelGGL(k_gather, dim3(TSEQ), dim3(256), 0, stream, x, E, emb, bar, onep);
  if (big)
    hipLaunchKernelGGL(k_cast, dim3(NL), dim3(256), 0, stream, W_last, wl16);
  hipLaunchKernelGGL(k_gi, dim3(TSEQ / 64, H3 / 64, 2), dim3(256), 0, stream,
                     emb, Wih_f, bih_f, Wih_b, bih_b, GIp);
  hipLaunchKernelGGL(k_enc, dim3(NWG), dim3(TPB), 0, stream,
                     Whh_f, bhh_f, Whh_b, bhh_b, GIp, hbF, hbB, hF, hB, bar, onep);
  if (big)
    hipLaunchKernelGGL(k_dec<1>, dim3(NWG), dim3(TPB), 0, stream,
                       W_mid, b_mid, W_len, b_len, Wih_d, bih_d, bhh_d,
                       W_last, wl16, L, out, hF, hB, sent, hD, wbV, wbI, bar, onep);
  else
    hipLaunchKernelGGL(k_dec<0>, dim3(NWG), dim3(TPB), 0, stream,
                       W_mid, b_mid, W_len, b_len, Wih_d, bih_d, bhh_d,
                       W_last, wl16, L, out, hF, hB, sent, hD, wbV, wbI, bar, onep);
}

// Round 20
// 5272.421 us; speedup vs baseline: 1.0585x; 1.0585x over previous
//
#include <hip/hip_runtime.h>
#include <math.h>

#define NWG 256
#define TPB 512
#define BSLOT 32   // uints per 128B barrier slot

static constexpr int H    = 2048;
static constexpr int H3   = 6144;
static constexpr int TDIM = 1024;
static constexpr int TSEQ = 512;
static constexpr int NL   = 50000;
static constexpr int ML   = 50;
static constexpr int DK   = 4096;

typedef unsigned int v4u __attribute__((ext_vector_type(4)));

// workspace layout (bytes, 16B aligned)
static constexpr size_t OFF_EMB  = 0;
static constexpr size_t OFF_GI   = OFF_EMB + (size_t)TSEQ * TDIM * 4;   // 2 MB
static constexpr size_t OFF_BAR  = OFF_GI + (size_t)2 * TSEQ * H3 * 4;  // +25.2 MB
static constexpr size_t OFF_HBF  = OFF_BAR + (size_t)64 * BSLOT * 4;    // 8 KB barrier block
static constexpr size_t OFF_HBB  = OFF_HBF + (size_t)2 * H * 4;
static constexpr size_t OFF_HF   = OFF_HBB + (size_t)2 * H * 4;
static constexpr size_t OFF_HB   = OFF_HF + (size_t)H * 4;
static constexpr size_t OFF_SENT = OFF_HB + (size_t)H * 4;
static constexpr size_t OFF_HD   = OFF_SENT + (size_t)H * 4;
static constexpr size_t OFF_WBV  = OFF_HD + (size_t)H * 4;
static constexpr size_t OFF_WBI  = OFF_WBV + (size_t)NWG * 4;
static constexpr size_t OFF_ONE  = OFF_WBI + (size_t)NWG * 4;
static constexpr size_t OFF_WL16 = ((OFF_ONE + 64) + 255) & ~(size_t)255;
static constexpr size_t WS_NEED  = OFF_WL16;                             // ~27.5 MB
static constexpr size_t WS_BIG   = OFF_WL16 + (size_t)NL * H * 2;        // +204.8 MB

// ---------- device-coherent (sc0 sc1) ops: mutable cross-WG data only ----------
__device__ __forceinline__ float4 cld4(const float4* p) {
  float4 v;
  asm volatile("global_load_dwordx4 %0, %1, off sc0 sc1\n\ts_waitcnt vmcnt(0)"
               : "=v"(v) : "v"(p) : "memory");
  return v;
}
__device__ __forceinline__ float cld1(const float* p) {
  float v;
  asm volatile("global_load_dword %0, %1, off sc0 sc1\n\ts_waitcnt vmcnt(0)"
               : "=v"(v) : "v"(p) : "memory");
  return v;
}
__device__ __forceinline__ int cldi(const int* p) {
  int v;
  asm volatile("global_load_dword %0, %1, off sc0 sc1\n\ts_waitcnt vmcnt(0)"
               : "=v"(v) : "v"(p) : "memory");
  return v;
}
__device__ __forceinline__ void cst1(float* p, float v) {
  asm volatile("global_store_dword %0, %1, off sc0 sc1" :: "v"(p), "v"(v) : "memory");
}
__device__ __forceinline__ void csti(int* p, int v) {
  asm volatile("global_store_dword %0, %1, off sc0 sc1" :: "v"(p), "v"(v) : "memory");
}

__device__ __forceinline__ float dp4(float4 a, float4 b, float s) {
  s = fmaf(a.x, b.x, s);
  s = fmaf(a.y, b.y, s);
  s = fmaf(a.z, b.z, s);
  s = fmaf(a.w, b.w, s);
  return s;
}
__device__ __forceinline__ float wred(float s) {
  #pragma unroll
  for (int m = 32; m > 0; m >>= 1) s += __shfl_xor(s, m, 64);
  return s;
}
__device__ __forceinline__ float u2lo(unsigned u) { return __uint_as_float(u << 16); }
__device__ __forceinline__ float u2hi(unsigned u) { return __uint_as_float(u & 0xffff0000u); }

// ---- three-tier encoder weight store (per wave: 2 h-indices, 6 rows) ----
#define DECL8(p)  float4 p##0, p##1, p##2, p##3, p##4, p##5, p##6, p##7
#define LOAD8(p, base) do { const float4* _r = (base); \
  p##0 = _r[lane];       p##1 = _r[lane + 64];  p##2 = _r[lane + 128]; \
  p##3 = _r[lane + 192]; p##4 = _r[lane + 256]; p##5 = _r[lane + 320]; \
  p##6 = _r[lane + 384]; p##7 = _r[lane + 448]; } while (0)
#define SC4(v) do { (v).x *= one; (v).y *= one; (v).z *= one; (v).w *= one; } while (0)
#define SCALE8(p) do { SC4(p##0); SC4(p##1); SC4(p##2); SC4(p##3); \
                       SC4(p##4); SC4(p##5); SC4(p##6); SC4(p##7); } while (0)
// acc: a0r,a0z,a0n (regs) a1r,a1z (LDS) a1n (stream, L2-cached)
#define STEPK(k) { float4 hv = h4[lane + (k << 6)]; \
  a0r = dp4(wA##k, hv, a0r); \
  a0z = dp4(wB##k, hv, a0z); \
  a0n = dp4(wC##k, hv, a0n); \
  a1r = dp4(lwW[((k) << 6) + lane], hv, a1r); \
  a1z = dp4(lwW[(((k) + 8) << 6) + lane], hv, a1z); \
  a1n = dp4(rN1[lane + ((k) << 6)], hv, a1n); }

// MONOTONE FENCE-FREE barrier: RELAXED agent atomics only, counters never
// reset, waiters poll top >= phase*nGrp. No release/acquire -> no per-step
// L2 writeback/invalidate. Mutable data moves via sc0sc1.
__device__ __forceinline__ void hbar(unsigned* bar, int gslot, int tslot,
                                     unsigned phase, unsigned grpSize, unsigned nGrp) {
  __syncthreads();
  if (threadIdx.x == 0) {
    unsigned a = __hip_atomic_fetch_add(bar + (size_t)gslot * BSLOT, 1u,
                                        __ATOMIC_RELAXED, __HIP_MEMORY_SCOPE_AGENT);
    if (a == phase * grpSize - 1u)
      __hip_atomic_fetch_add(bar + (size_t)tslot * BSLOT, 1u,
                             __ATOMIC_RELAXED, __HIP_MEMORY_SCOPE_AGENT);
    unsigned c;
    do {
      __builtin_amdgcn_s_sleep(1);
      c = __hip_atomic_load(bar + (size_t)tslot * BSLOT,
                            __ATOMIC_RELAXED, __HIP_MEMORY_SCOPE_AGENT);
    } while (c < phase * nGrp);
    asm volatile("" ::: "memory");
  }
  __syncthreads();
}

__global__ __launch_bounds__(256) void k_gather(const int* __restrict__ x,
                                                const float* __restrict__ E,
                                                float* __restrict__ emb,
                                                unsigned* __restrict__ bar,
                                                float* __restrict__ onep) {
  if (blockIdx.x == 0) {
    for (int i = threadIdx.x; i < 64 * BSLOT; i += 256) bar[i] = 0u;
    if (threadIdx.x == 0) *onep = 1.0f;   // opaque runtime 1.0
  }
  int t = blockIdx.x;
  const float4* src = (const float4*)(E + (size_t)x[t] * TDIM);
  float4* dst = (float4*)(emb + (size_t)t * TDIM);
  dst[threadIdx.x] = src[threadIdx.x];
}

// one-time W_last fp32 -> bf16 (RTNE), row-major
__global__ __launch_bounds__(256) void k_cast(const float* __restrict__ W,
                                              unsigned short* __restrict__ O) {
  size_t i = (size_t)blockIdx.x * 2048 + (size_t)threadIdx.x * 8;
  float4 a = ((const float4*)(W + i))[0];
  float4 b = ((const float4*)(W + i))[1];
  #define CVT(f) ((( __float_as_uint(f) + 0x7FFFu + ((__float_as_uint(f) >> 16) & 1u)) >> 16) & 0xFFFFu)
  uint4 o;
  o.x = CVT(a.x) | (CVT(a.y) << 16);
  o.y = CVT(a.z) | (CVT(a.w) << 16);
  o.z = CVT(b.x) | (CVT(b.y) << 16);
  o.w = CVT(b.z) | (CVT(b.w) << 16);
  #undef CVT
  ((uint4*)(O + i))[0] = o;
}

// GI[dir][t][j] = emb[(dir? 511-t : t)] . Wih_dir[j] + bih_dir[j]
__global__ __launch_bounds__(256) void k_gi(const float* __restrict__ emb,
                                            const float* __restrict__ Wf,
                                            const float* __restrict__ bf_,
                                            const float* __restrict__ Wb,
                                            const float* __restrict__ bb_,
                                            float* __restrict__ GI) {
  __shared__ float As[64][33];
  __shared__ float Bs[64][33];
  const int dir = blockIdx.z;
  const float* W  = dir ? Wb  : Wf;
  const float* bi = dir ? bb_ : bf_;
  const int t0 = blockIdx.x * 64, j0 = blockIdx.y * 64;
  const int tid = threadIdx.x;
  const int tx = tid & 15, ty = tid >> 4;
  float acc[4][4] = {};
  for (int k0 = 0; k0 < TDIM; k0 += 32) {
    #pragma unroll
    for (int i = 0; i < 8; ++i) {
      int idx = tid + (i << 8);
      int r = idx >> 5, kk = idx & 31;
      int tg = t0 + r;
      int arow = dir ? (TSEQ - 1 - tg) : tg;
      As[r][kk] = emb[(size_t)arow * TDIM + k0 + kk];
      Bs[r][kk] = W[(size_t)(j0 + r) * TDIM + k0 + kk];
    }
    __syncthreads();
    #pragma unroll
    for (int kk = 0; kk < 32; ++kk) {
      float a[4], b[4];
      #pragma unroll
      for (int i = 0; i < 4; ++i) a[i] = As[ty * 4 + i][kk];
      #pragma unroll
      for (int jj = 0; jj < 4; ++jj) b[jj] = Bs[tx * 4 + jj][kk];
      #pragma unroll
      for (int i = 0; i < 4; ++i)
        #pragma unroll
        for (int jj = 0; jj < 4; ++jj) acc[i][jj] = fmaf(a[i], b[jj], acc[i][jj]);
    }
    __syncthreads();
  }
  float* C = GI + (size_t)dir * TSEQ * H3;
  #pragma unroll
  for (int i = 0; i < 4; ++i)
    #pragma unroll
    for (int jj = 0; jj < 4; ++jj) {
      int t = t0 + ty * 4 + i, col = j0 + tx * 4 + jj;
      C[(size_t)t * H3 + col] = acc[i][jj] + bi[col];
    }
}

// ===================== ENCODER-ONLY persistent kernel (round-14, unchanged) ====
__global__ __launch_bounds__(TPB, 2) void k_enc(
    const float* __restrict__ Whh_f, const float* __restrict__ bhh_f,
    const float* __restrict__ Whh_b, const float* __restrict__ bhh_b,
    const float* __restrict__ GI,
    float* __restrict__ hbF, float* __restrict__ hbB,
    float* __restrict__ hF, float* __restrict__ hB,
    unsigned* __restrict__ bar, const float* __restrict__ onep) {
  __shared__ float  ldsH[H];                // 8 KB (h broadcast)
  __shared__ float4 ldsW[8 * 16 * 64];      // 128 KB (weight tier 2)
  const int tid  = threadIdx.x;
  const int wg   = blockIdx.x;
  const int lane = tid & 63;
  const int w    = tid >> 6;
  const float4* h4 = (const float4*)ldsH;
  const float one = *onep;    // opaque 1.0f (SGPR)

  const int d   = wg >> 7;          // 0=fwd, 1=bwd
  const int wid = wg & 127;
  const int j0  = (((wid << 3) | w) << 1);   // this wave's 2 h-indices
  const float* Whh = d ? Whh_b : Whh_f;
  const float* bhh = d ? bhh_b : bhh_f;
  const float* GId = GI + (size_t)d * TSEQ * H3;
  float* hbufD = d ? hbB : hbF;
  float* hT    = d ? hB  : hF;
  const int gslot = d * 16 + (wid & 7), tslot = d * 16 + 8;
  unsigned ep = 0;

  // tier 1: rows r0,z0,n0 -> 24 NAMED float4 (96 VGPRs)
  DECL8(wA); DECL8(wB); DECL8(wC);
  LOAD8(wA, (const float4*)(Whh + (size_t)(0 * H + j0 + 0) * H));
  LOAD8(wB, (const float4*)(Whh + (size_t)(1 * H + j0 + 0) * H));
  LOAD8(wC, (const float4*)(Whh + (size_t)(2 * H + j0 + 0) * H));

  // tier 2: rows r1,z1 -> LDS (per-wave 16 KB block, lane-major, conflict-free)
  float4* lwW = &ldsW[(size_t)w << 10];    // w * 1024 float4
  {
    const float4* rR1 = (const float4*)(Whh + (size_t)(0 * H + j0 + 1) * H);
    const float4* rZ1 = (const float4*)(Whh + (size_t)(1 * H + j0 + 1) * H);
    #pragma unroll
    for (int k = 0; k < 8; ++k) lwW[(k << 6) + lane]       = rR1[lane + (k << 6)];
    #pragma unroll
    for (int k = 0; k < 8; ++k) lwW[((k + 8) << 6) + lane] = rZ1[lane + (k << 6)];
  }

  // tier 3: row n1 -> streamed each step (plain loads; 2.1 MB/XCD -> L2-hit)
  const float4* rN1 = (const float4*)(Whh + (size_t)(2 * H + j0 + 1) * H);

  float b_r = 0.f, b_z = 0.f, b_n = 0.f, g_r = 0.f, g_z = 0.f, g_n = 0.f;
  if (lane < 2) {
    b_r = bhh[j0 + lane]; b_z = bhh[H + j0 + lane]; b_n = bhh[2 * H + j0 + lane];
    g_r = GId[j0 + lane]; g_z = GId[H + j0 + lane]; g_n = GId[2 * H + j0 + lane];
  }
  // t = 0: h(0)=0 -> h(1) directly, no matvec, no prior barrier
  if (lane < 2) {
    float r = 1.f / (1.f + expf(-(g_r + b_r)));
    float z = 1.f / (1.f + expf(-(g_z + b_z)));
    float n = tanhf(g_n + r * b_n);
    cst1(&hbufD[H + j0 + lane], (1.f - z) * n);
    const float* gp = GId + (size_t)1 * H3 + j0 + lane;
    g_r = gp[0]; g_z = gp[H]; g_n = gp[2 * H];
  }
  hbar(bar, gslot, tslot, ++ep, 16u, 8u);   // also covers the LDS weight fill

  for (int t = 1; t < TSEQ; ++t) {
    // loop-carried x1.0 on the register tier: loads cannot be re-sunk
    SCALE8(wA); SCALE8(wB); SCALE8(wC);

    ((float4*)ldsH)[tid] = cld4((const float4*)hbufD + ((t & 1) << 9) + tid);
    __syncthreads();
    float a0r = 0.f, a0z = 0.f, a0n = 0.f, a1r = 0.f, a1z = 0.f, a1n = 0.f;
    STEPK(0) STEPK(1) STEPK(2) STEPK(3) STEPK(4) STEPK(5) STEPK(6) STEPK(7)
    a0r = wred(a0r); a0z = wred(a0z); a0n = wred(a0n);
    a1r = wred(a1r); a1z = wred(a1z); a1n = wred(a1n);
    if (lane < 2) {
      float aR = lane ? a1r : a0r;
      float aZ = lane ? a1z : a0z;
      float aN = lane ? a1n : a0n;
      float hold = ldsH[j0 + lane];
      float r = 1.f / (1.f + expf(-(g_r + b_r + aR)));
      float z = 1.f / (1.f + expf(-(g_z + b_z + aZ)));
      float n = tanhf(g_n + r * (aN + b_n));
      cst1(&hbufD[(size_t)((t + 1) & 1) * H + j0 + lane], (1.f - z) * n + z * hold);
      if (t < TSEQ - 1) {
        const float* gp = GId + (size_t)(t + 1) * H3 + j0 + lane;
        g_r = gp[0]; g_z = gp[H]; g_n = gp[2 * H];
      }
    }
    hbar(bar, gslot, tslot, ++ep, 16u, 8u);
  }
  if (wid == 0) {   // final h = buf0 (coherent read; plain store, kernel-end flush)
    float4 hv = cld4((const float4*)hbufD + tid);
    ((float4*)hT)[tid] = hv;
  }
}

// ===================== mid/len + decoder kernel (r14 + nt on Wl16) ==========
template <int BF16>
__global__ __launch_bounds__(TPB, 2) void k_dec(
    const float* __restrict__ W_mid, const float* __restrict__ b_mid,
    const float* __restrict__ W_len, const float* __restrict__ b_len,
    const float* __restrict__ Wih_d, const float* __restrict__ bih_d,
    const float* __restrict__ bhh_d,
    const float* __restrict__ W_last, const unsigned short* __restrict__ Wl16,
    const float* __restrict__ L,
    float* __restrict__ out,
    const float* __restrict__ hF, const float* __restrict__ hB,
    float* __restrict__ sent, float* __restrict__ hD,
    float* __restrict__ wbV, int* __restrict__ wbI,
    unsigned* __restrict__ bar) {
  __shared__ float ldsH[H];       // 8 KB
  __shared__ float ldsC[2 * H];   // 16 KB
  __shared__ float rv[NWG];
  __shared__ int   ri[NWG];
  __shared__ float tv1[8], tv2[8];
  __shared__ int   ti1[8], ti2[8];
  __shared__ float scV[2];
  __shared__ int   scI[2];

  const int tid  = threadIdx.x;
  const int wg   = blockIdx.x;
  const int lane = tid & 63;
  const int w    = tid >> 6;
  const float4* h4 = (const float4*)ldsH;
  const int jd = (wg << 3) | w;   // decoder/mid h-index, 1 per wave
  unsigned fp = 0;

  // ---------------- sent = [hF,hB] @ W_mid.T + b_mid ----------------
  ((float4*)ldsC)[tid]       = ((const float4*)hF)[tid];   // kernel-boundary coherent
  ((float4*)ldsC)[TPB + tid] = ((const float4*)hB)[tid];
  __syncthreads();
  {
    const float4* wm = (const float4*)W_mid + (size_t)jd * (DK / 4);
    const float4* c4 = (const float4*)ldsC;
    float s = 0.f;
    #pragma unroll
    for (int k = 0; k < 16; ++k) {
      int c = lane + (k << 6);
      s = dp4(wm[c], c4[c], s);
    }
    s = wred(s);
    if (lane == 0) cst1(&sent[jd], s + b_mid[jd]);
  }
  hbar(bar, 32 + (wg & 7), 40, ++fp, 32u, 8u);

  // stage sent -> ldsH (lscores + A(0) carry tail)
  ((float4*)ldsH)[tid] = cld4((const float4*)sent + tid);
  __syncthreads();

  // ---------------- lscores ----------------
  if (jd < ML) {
    const float4* wl = (const float4*)W_len + (size_t)jd * (H / 4);
    float s = 0.f;
    #pragma unroll
    for (int k = 0; k < 8; ++k) {
      int c = lane + (k << 6);
      s = dp4(wl[c], h4[c], s);
    }
    s = wred(s);
    if (lane == 0) out[jd] = s + b_len[jd];
  }

  // decoder per-wave gate constants (decoder h0 = 0 -> gh == bhh_d)
  float cr = 0.f, cz = 0.f, cni = 0.f, cnh = 0.f;
  if (lane == 0) {
    cr  = bih_d[jd] + bhh_d[jd];
    cz  = bih_d[H + jd] + bhh_d[H + jd];
    cni = bih_d[2 * H + jd];
    cnh = bhh_d[2 * H + jd];
  }

  // A(0) carry: head = 0, tail = sent
  ((float4*)ldsC)[tid]       = make_float4(0.f, 0.f, 0.f, 0.f);
  ((float4*)ldsC)[TPB + tid] = ((const float4*)ldsH)[tid];
  __syncthreads();

  // ---------------- decoder: 50 steps, 2 barriers each ----------------
  for (int st = 0; st < ML; ++st) {
    if (st > 0) {
      // local finalize of previous step's argmax in every WG
      if (tid < NWG) { rv[tid] = cld1(wbV + tid); ri[tid] = cldi(wbI + tid); }
      __syncthreads();
      for (int off = NWG / 2; off > 0; off >>= 1) {
        if (tid < off) {
          float v2 = rv[tid + off]; int i2 = ri[tid + off];
          if (v2 > rv[tid] || (v2 == rv[tid] && i2 < ri[tid])) { rv[tid] = v2; ri[tid] = i2; }
        }
        __syncthreads();
      }
      int pred = ri[0];
      if (wg == 0 && tid == 0) out[ML + (size_t)ML * NL + (st - 1)] = (float)pred;
      // carry: head = hD(st-1) (still in ldsH), tail = L[pred] (read-only input)
      ((float4*)ldsC)[tid]       = ((const float4*)ldsH)[tid];
      ((float4*)ldsC)[TPB + tid] = ((const float4*)(L + (size_t)pred * H))[tid];
      __syncthreads();
    }
    // phase A: gi = Wih_d @ carry ; gates ; publish hD (fp32 end-to-end)
    // Wih_d uses PLAIN cached loads -> stays L3-resident (Wl16 is nt below)
    {
      const float4* c4 = (const float4*)ldsC;
      const float4* r0 = (const float4*)Wih_d + (size_t)jd * (DK / 4);
      const float4* r1 = r0 + (size_t)H * (DK / 4);
      const float4* r2 = r1 + (size_t)H * (DK / 4);
      float s0 = 0.f, s1 = 0.f, s2 = 0.f;
      #pragma unroll 4
      for (int k = 0; k < 16; ++k) {
        int c = lane + (k << 6);
        float4 cv = c4[c];
        s0 = dp4(r0[c], cv, s0);
        s1 = dp4(r1[c], cv, s1);
        s2 = dp4(r2[c], cv, s2);
      }
      s0 = wred(s0); s1 = wred(s1); s2 = wred(s2);
      if (lane == 0) {
        float r = 1.f / (1.f + expf(-(s0 + cr)));
        float z = 1.f / (1.f + expf(-(s1 + cz)));
        float n = tanhf(s2 + cni + r * cnh);
        cst1(&hD[jd], (1.f - z) * n);
      }
    }
    hbar(bar, 32 + (wg & 7), 40, ++fp, 32u, 8u);   // hD visible

    // phase B: scores = hD @ W_last.T ; argmax candidates
    ((float4*)ldsH)[tid] = cld4((const float4*)hD + tid);
    __syncthreads();
    float* outs = out + ML + (size_t)st * NL;
    if (BF16) {
      // bf16 stream with NON-TEMPORAL loads; nt stores for the score output.
      float4 hvb[8];
      #pragma unroll
      for (int k = 0; k < 4; ++k) {
        int i = (lane + (k << 6)) << 1;
        hvb[2 * k]     = h4[i];
        hvb[2 * k + 1] = h4[i + 1];
      }
      float v1 = -3.4e38f, v2 = -3.4e38f;
      int   i1 = 0x7FFFFFFF, i2 = 0x7FFFFFFF;
      for (int chunk = 0; chunk < 25; ++chunk) {
        int r = (chunk << 11) + jd;
        if (r < NL) {
          const v4u* row = (const v4u*)(Wl16 + (size_t)r * H);
          float sc = 0.f;
          #pragma unroll
          for (int k = 0; k < 4; ++k) {
            v4u u = __builtin_nontemporal_load(row + lane + (k << 6));
            float4 ha = hvb[2 * k], hb = hvb[2 * k + 1];
            sc = fmaf(u2lo(u[0]), ha.x, sc); sc = fmaf(u2hi(u[0]), ha.y, sc);
            sc = fmaf(u2lo(u[1]), ha.z, sc); sc = fmaf(u2hi(u[1]), ha.w, sc);
            sc = fmaf(u2lo(u[2]), hb.x, sc); sc = fmaf(u2hi(u[2]), hb.y, sc);
            sc = fmaf(u2lo(u[3]), hb.z, sc); sc = fmaf(u2hi(u[3]), hb.w, sc);
          }
          sc = wred(sc);
          if (lane == 0) __builtin_nontemporal_store(sc, &outs[r]);
          if (sc > v1 || (sc == v1 && r < i1)) { v2 = v1; i2 = i1; v1 = sc; i1 = r; }
          else if (sc > v2 || (sc == v2 && r < i2)) { v2 = sc; i2 = r; }
        }
      }
      if (lane == 0) { tv1[w] = v1; ti1[w] = i1; tv2[w] = v2; ti2[w] = i2; }
      __syncthreads();
      if (tid == 0) {   // WG top-2 by approx score
        float b1 = -3.4e38f, b2 = -3.4e38f;
        int   x1 = 0x7FFFFFFF, x2 = 0x7FFFFFFF;
        #pragma unroll
        for (int q = 0; q < 8; ++q) {
          float a1 = tv1[q]; int y1 = ti1[q];
          float a2 = tv2[q]; int y2 = ti2[q];
          if (a1 > b1 || (a1 == b1 && y1 < x1)) { b2 = b1; x2 = x1; b1 = a1; x1 = y1; }
          else if (a1 > b2 || (a1 == b2 && y1 < x2)) { b2 = a1; x2 = y1; }
          if (a2 > b1 || (a2 == b1 && y2 < x1)) { b2 = b1; x2 = x1; b1 = a2; x1 = y2; }
          else if (a2 > b2 || (a2 == b2 && y2 < x2)) { b2 = a2; x2 = y2; }
        }
        scI[0] = x1; scI[1] = x2;
      }
      __syncthreads();
      if (w < 2) {   // exact fp32 rescore (identical sum order everywhere)
        int c = scI[w];
        const float4* wl = (const float4*)W_last + (size_t)c * (H / 4);
        float s = 0.f;
        #pragma unroll
        for (int k = 0; k < 8; ++k) {
          int cc = lane + (k << 6);
          s = dp4(wl[cc], h4[cc], s);
        }
        s = wred(s);
        if (lane == 0) scV[w] = s;
      }
      __syncthreads();
      if (tid == 0) {
        float v = scV[0]; int i0 = scI[0];
        if (scV[1] > v || (scV[1] == v && scI[1] < i0)) { v = scV[1]; i0 = scI[1]; }
        cst1(&wbV[wg], v); csti(&wbI[wg], i0);
      }
    } else {
      // fp32 fallback (ws too small for bf16 copy)
      float4 hv[8];
      #pragma unroll
      for (int k = 0; k < 8; ++k) hv[k] = h4[lane + (k << 6)];
      float bv = -3.4e38f; int bix = 0x7FFFFFFF;
      for (int chunk = 0; chunk < 25; ++chunk) {
        int r = (chunk << 11) + jd;
        if (r < NL) {
          const float4* wl = (const float4*)W_last + (size_t)r * (H / 4);
          float sc = 0.f;
          #pragma unroll
          for (int k = 0; k < 8; ++k) sc = dp4(wl[lane + (k << 6)], hv[k], sc);
          sc = wred(sc);
          if (lane == 0) {
            outs[r] = sc;
            if (sc > bv) { bv = sc; bix = r; }
          }
        }
      }
      if (lane == 0) { tv1[w] = bv; ti1[w] = bix; }
      __syncthreads();
      if (tid == 0) {
        float v = tv1[0]; int i0 = ti1[0];
        #pragma unroll
        for (int q = 1; q < 8; ++q)
          if (tv1[q] > v || (tv1[q] == v && ti1[q] < i0)) { v = tv1[q]; i0 = ti1[q]; }
        cst1(&wbV[wg], v); csti(&wbI[wg], i0);
      }
    }
    hbar(bar, 32 + (wg & 7), 40, ++fp, 32u, 8u);   // wb visible
  }

  // final pred (st = 49)
  if (wg == 0) {
    if (tid < NWG) { rv[tid] = cld1(wbV + tid); ri[tid] = cldi(wbI + tid); }
    __syncthreads();
    for (int off = NWG / 2; off > 0; off >>= 1) {
      if (tid < off) {
        float v2 = rv[tid + off]; int i2 = ri[tid + off];
        if (v2 > rv[tid] || (v2 == rv[tid] && i2 < ri[tid])) { rv[tid] = v2; ri[tid] = i2; }
      }
      __syncthreads();
    }
    if (tid == 0) out[ML + (size_t)ML * NL + (ML - 1)] = (float)ri[0];
  }
}

extern "C" void kernel_launch(void* const* d_in, const int* in_sizes, int n_in,
                              void* d_out, int out_size, void* d_ws, size_t ws_size,
                              hipStream_t stream) {
  (void)in_sizes; (void)n_in; (void)out_size;
  if (ws_size < WS_NEED) return;
  const bool big = (ws_size >= WS_BIG);

  const int*   x     = (const int*)  d_in[0];
  const float* E     = (const float*)d_in[1];
  const float* L     = (const float*)d_in[2];
  const float* Wih_f = (const float*)d_in[3];
  const float* Whh_f = (const float*)d_in[4];
  const float* bih_f = (const float*)d_in[5];
  const float* bhh_f = (const float*)d_in[6];
  const float* Wih_b = (const float*)d_in[7];
  const float* Whh_b = (const float*)d_in[8];
  const float* bih_b = (const float*)d_in[9];
  const float* bhh_b = (const float*)d_in[10];
  const float* W_mid = (const float*)d_in[11];
  const float* b_mid = (const float*)d_in[12];
  const float* W_len = (const float*)d_in[13];
  const float* b_len = (const float*)d_in[14];
  const float* Wih_d = (const float*)d_in[15];
  // d_in[16] = Whh_d: unused (decoder hidden is 0 -> gh == bhh_d)
  const float* bih_d = (const float*)d_in[17];
  const float* bhh_d = (const float*)d_in[18];
  const float* W_last= (const float*)d_in[19];
  float* out = (float*)d_out;
  char* ws = (char*)d_ws;

  float*    emb  = (float*)(ws + OFF_EMB);
  float*    GIp  = (float*)(ws + OFF_GI);
  unsigned* bar  = (unsigned*)(ws + OFF_BAR);
  float*    hbF  = (float*)(ws + OFF_HBF);
  float*    hbB  = (float*)(ws + OFF_HBB);
  float*    hF   = (float*)(ws + OFF_HF);
  float*    hB   = (float*)(ws + OFF_HB);
  float*    sent = (float*)(ws + OFF_SENT);
  float*    hD   = (float*)(ws + OFF_HD);
  float*    wbV  = (float*)(ws + OFF_WBV);
  int*      wbI  = (int*)  (ws + OFF_WBI);
  float*    onep = (float*)(ws + OFF_ONE);
  unsigned short* wl16 = (unsigned short*)(ws + OFF_WL16);

  hipLaunchKernelGGL(k_gather, dim3(TSEQ), dim3(256), 0, stream, x, E, emb, bar, onep);
  if (big)
    hipLaunchKernelGGL(k_cast, dim3(NL), dim3(256), 0, stream, W_last, wl16);
  hipLaunchKernelGGL(k_gi, dim3(TSEQ / 64, H3 / 64, 2), dim3(256), 0, stream,
                     emb, Wih_f, bih_f, Wih_b, bih_b, GIp);
  hipLaunchKernelGGL(k_enc, dim3(NWG), dim3(TPB), 0, stream,
                     Whh_f, bhh_f, Whh_b, bhh_b, GIp, hbF, hbB, hF, hB, bar, onep);
  if (big)
    hipLaunchKernelGGL(k_dec<1>, dim3(NWG), dim3(TPB), 0, stream,
                       W_mid, b_mid, W_len, b_len, Wih_d, bih_d, bhh_d,
                       W_last, wl16, L, out, hF, hB, sent, hD, wbV, wbI, bar);
  else
    hipLaunchKernelGGL(k_dec<0>, dim3(NWG), dim3(TPB), 0, stream,
                       W_mid, b_mid, W_len, b_len, Wih_d, bih_d, bhh_d,
                       W_last, wl16, L, out, hF, hB, sent, hD, wbV, wbI, bar);
}